// Round 11
// baseline (366.108 us; speedup 1.0000x reference)
//
#include <hip/hip_runtime.h>
#include <hip/hip_fp16.h>
#include <math.h>

// ---------------------------------------------------------------------------
// GCN 3-layer forward on MI355X.
// Round 10 change: fused kernel's static 64KB LDS throttled the edge-atomic
// blocks to 8 waves/CU (112us). W1 is now pre-converted ONCE (1-block kernel)
// to fragment layout (bf16 hi/lo, transposed, swizzled) in a 64KB GLOBAL
// buffer; fused gemm blocks read B-frags straight from global (L1/L2-hot).
// Fused kernel has NO LDS -> edge blocks back to full occupancy; edge blocks
// dispatched first. Layers 2/3 keep the LDS gemm.
// ---------------------------------------------------------------------------

typedef __bf16 bf16x8 __attribute__((ext_vector_type(8)));
typedef float f32x4 __attribute__((ext_vector_type(4)));

union BF8 {
  unsigned short u[8];
  uint4 q;
  bf16x8 v;
};

__device__ __forceinline__ unsigned short rne_bf16(float f) {
  unsigned u = __float_as_uint(f);
  u += 0x7fff + ((u >> 16) & 1);
  return (unsigned short)(u >> 16);
}
__device__ __forceinline__ float bf16_to_f(unsigned short h) {
  return __uint_as_float((unsigned)h << 16);
}

// ---- one-block W1 -> fragment-layout converter (64KB global WTg) ----------
// WTg[h][n][kk]: h=hi/lo, n=col 0..127, kk = k0 ^ ((n&7)<<3), bf16.
__global__ __launch_bounds__(256) void prep_w1_kernel(const float* __restrict__ W,
    unsigned short* __restrict__ WTg) {
  const int t = threadIdx.x;
#pragma unroll
  for (int it = 0; it < 8; ++it) {
    int n = t % 128;
    int kc = it * 2 + t / 128;
    int k0 = kc * 8;
    BF8 hh, ll;
#pragma unroll
    for (int j = 0; j < 8; ++j) {
      float w = W[(size_t)(k0 + j) * 128 + n];
      unsigned short hb = rne_bf16(w);
      hh.u[j] = hb;
      ll.u[j] = rne_bf16(w - bf16_to_f(hb));
    }
    int kk = k0 ^ ((n & 7) << 3);
    *(uint4*)&WTg[(size_t)n * 128 + kk] = hh.q;
    *(uint4*)&WTg[16384 + (size_t)n * 128 + kk] = ll.q;
  }
}

// ---- LDS-free MFMA gemm body reading pre-converted WTg (NCOL=128) ---------
__device__ __forceinline__ void gemm_body_g(const float* __restrict__ A,
    const unsigned short* __restrict__ WTg, unsigned short* __restrict__ Ch,
    int M, int bid) {
  constexpr int NF = 8;
  const int t = threadIdx.x;
  const int wv = t >> 6;
  const int l = t & 63;
  const int lr = l & 15;
  const int lg = l >> 4;
  const int arow_i = bid * 64 + wv * 16 + lr;
  const bool rv = arow_i < M;
  const float* arow = A + (size_t)arow_i * 128;

  f32x4 acc[NF] = {};
  float4 p0 = make_float4(0.f, 0.f, 0.f, 0.f), p1 = p0;
  if (rv) {
    p0 = *(const float4*)&arow[lg * 8];
    p1 = *(const float4*)&arow[lg * 8 + 4];
  }
#pragma unroll 1
  for (int ks = 0; ks < 4; ++ks) {
    int nkb = ((ks < 3) ? (ks + 1) * 32 : ks * 32) + lg * 8;
    float4 q0 = make_float4(0.f, 0.f, 0.f, 0.f), q1 = q0;
    if (rv) {
      q0 = *(const float4*)&arow[nkb];
      q1 = *(const float4*)&arow[nkb + 4];
    }
    float av[8] = {p0.x, p0.y, p0.z, p0.w, p1.x, p1.y, p1.z, p1.w};
    BF8 ah, al;
#pragma unroll
    for (int j = 0; j < 8; ++j) {
      unsigned short hb = rne_bf16(av[j]);
      ah.u[j] = hb;
      al.u[j] = rne_bf16(av[j] - bf16_to_f(hb));
    }
    int kidx = ks * 32 + lg * 8;
#pragma unroll
    for (int nf = 0; nf < NF; ++nf) {
      int n = nf * 16 + lr;
      int kk = kidx ^ ((n & 7) << 3);
      BF8 bh, bl;
      bh.q = *(const uint4*)&WTg[(size_t)n * 128 + kk];
      bl.q = *(const uint4*)&WTg[16384 + (size_t)n * 128 + kk];
      acc[nf] = __builtin_amdgcn_mfma_f32_16x16x32_bf16(ah.v, bh.v, acc[nf], 0, 0, 0);
      acc[nf] = __builtin_amdgcn_mfma_f32_16x16x32_bf16(al.v, bh.v, acc[nf], 0, 0, 0);
      acc[nf] = __builtin_amdgcn_mfma_f32_16x16x32_bf16(ah.v, bl.v, acc[nf], 0, 0, 0);
    }
    p0 = q0; p1 = q1;
  }
  const int orow0 = bid * 64 + wv * 16 + lg * 4;
#pragma unroll
  for (int j = 0; j < 4; ++j) {
    int orow = orow0 + j;
    if (orow < M) {
      unsigned short* hr = Ch + (size_t)orow * 128;
#pragma unroll
      for (int nf = 0; nf < NF; ++nf)
        hr[nf * 16 + lr] = __half_as_ushort(__float2half(acc[nf][j]));
    }
  }
}

// fused dispatch: blocks [0,edgeBlocks) = edge_pass (atomics start at t=0);
// blocks [edgeBlocks, edgeBlocks+gemmBlocks) = LDS-free layer-1 GEMM.
__global__ __launch_bounds__(256) void pre_gemm_fused_kernel(
    const float* __restrict__ x, const unsigned short* __restrict__ WT1g,
    unsigned short* __restrict__ Ch, int M,
    const int* __restrict__ ei, const float* __restrict__ ew,
    unsigned long long* __restrict__ packed, int* __restrict__ rank,
    int E, int edgeBlocks) {
  if ((int)blockIdx.x < edgeBlocks) {
    int e = blockIdx.x * 256 + threadIdx.x;
    if (e >= E) return;
    int d = ei[E + e];
    unsigned wfix = (unsigned)__float2uint_rn(ew[e] * 16777216.0f);  // Q24
    unsigned long long inc = (1ULL << 32) | (unsigned long long)wfix;
    unsigned long long old = atomicAdd(&packed[d], inc);
    rank[e] = (int)(old >> 32);
  } else {
    gemm_body_g(x, WT1g, Ch, M, blockIdx.x - edgeBlocks);
  }
}

// ---- LDS-staged MFMA gemm (layers 2,3; fp16 A input) -----------------------
template <int NCOL>
__global__ __launch_bounds__(256) void gemm_mfma_kernel(
    const unsigned short* __restrict__ Ah, const float* __restrict__ W,
    unsigned short* __restrict__ Ch, int M) {
  constexpr int NF = NCOL / 16;
  __shared__ __align__(16) unsigned short WT[2][NCOL][128];
  const int t = threadIdx.x;
  constexpr int KC_PER_IT = 256 / NCOL;
#pragma unroll
  for (int it = 0; it < 16 / KC_PER_IT; ++it) {
    int n = t % NCOL;
    int kc = it * KC_PER_IT + t / NCOL;
    int k0 = kc * 8;
    BF8 hh, ll;
#pragma unroll
    for (int j = 0; j < 8; ++j) {
      float w = W[(size_t)(k0 + j) * NCOL + n];
      unsigned short hb = rne_bf16(w);
      hh.u[j] = hb;
      ll.u[j] = rne_bf16(w - bf16_to_f(hb));
    }
    int kk = k0 ^ ((n & 7) << 3);
    *(uint4*)&WT[0][n][kk] = hh.q;
    *(uint4*)&WT[1][n][kk] = ll.q;
  }
  __syncthreads();

  const int wv = t >> 6;
  const int l = t & 63;
  const int lr = l & 15;
  const int lg = l >> 4;
  const int arow_i = blockIdx.x * 64 + wv * 16 + lr;
  const bool rv = arow_i < M;
  const unsigned short* arowh = Ah + (size_t)arow_i * 128;

  f32x4 acc[NF] = {};
  uint4 ph = make_uint4(0, 0, 0, 0);
  if (rv) ph = *(const uint4*)&arowh[lg * 8];
#pragma unroll 1
  for (int ks = 0; ks < 4; ++ks) {
    int nkb = ((ks < 3) ? (ks + 1) * 32 : ks * 32) + lg * 8;
    uint4 qh = make_uint4(0, 0, 0, 0);
    if (rv) qh = *(const uint4*)&arowh[nkb];
    float av[8];
    {
      union { uint4 q; __half2 h2[4]; } uu;
      uu.q = ph;
#pragma unroll
      for (int j = 0; j < 4; ++j) {
        float2 f = __half22float2(uu.h2[j]);
        av[j * 2] = f.x; av[j * 2 + 1] = f.y;
      }
    }
    BF8 ah, al;
#pragma unroll
    for (int j = 0; j < 8; ++j) {
      unsigned short hb = rne_bf16(av[j]);
      ah.u[j] = hb;
      al.u[j] = rne_bf16(av[j] - bf16_to_f(hb));
    }
    int kidx = ks * 32 + lg * 8;
    BF8 bh[NF], bl[NF];
#pragma unroll
    for (int nf = 0; nf < NF; ++nf) {
      int n = nf * 16 + lr;
      int kk = kidx ^ ((n & 7) << 3);
      bh[nf].q = *(const uint4*)&WT[0][n][kk];
      bl[nf].q = *(const uint4*)&WT[1][n][kk];
    }
#pragma unroll
    for (int nf = 0; nf < NF; ++nf) {
      acc[nf] = __builtin_amdgcn_mfma_f32_16x16x32_bf16(ah.v, bh[nf].v, acc[nf], 0, 0, 0);
      acc[nf] = __builtin_amdgcn_mfma_f32_16x16x32_bf16(al.v, bh[nf].v, acc[nf], 0, 0, 0);
      acc[nf] = __builtin_amdgcn_mfma_f32_16x16x32_bf16(ah.v, bl[nf].v, acc[nf], 0, 0, 0);
    }
    ph = qh;
  }
  const int orow0 = blockIdx.x * 64 + wv * 16 + lg * 4;
#pragma unroll
  for (int j = 0; j < 4; ++j) {
    int orow = orow0 + j;
    if (orow < M) {
      unsigned short* hr = Ch + (size_t)orow * NCOL;
#pragma unroll
      for (int nf = 0; nf < NF; ++nf)
        hr[nf * 16 + lr] = __half_as_ushort(__float2half(acc[nf][j]));
    }
  }
}

__global__ __launch_bounds__(256) void dinv_kernel(const unsigned long long* __restrict__ packed,
    float* __restrict__ dinv, int n) {
  int i = blockIdx.x * 256 + threadIdx.x;
  if (i >= n) return;
  float deg = 1.0f + (float)(unsigned)(packed[i] & 0xffffffffULL) * (1.0f / 16777216.0f);
  dinv[i] = 1.0f / sqrtf(deg);
}

// ---- 3-kernel exclusive scan of counts (hi32 of packed) -> row_ptr ---------
__global__ __launch_bounds__(1024) void scanA(const unsigned long long* __restrict__ packed,
    int* __restrict__ row_ptr, int* __restrict__ partials, int n) {
  __shared__ int sd[1024];
  int t = threadIdx.x;
  int i = blockIdx.x * 1024 + t;
  int v = (i < n) ? (int)(packed[i] >> 32) : 0;
  sd[t] = v;
  __syncthreads();
  for (int off = 1; off < 1024; off <<= 1) {
    int u = (t >= off) ? sd[t - off] : 0;
    __syncthreads();
    sd[t] += u;
    __syncthreads();
  }
  int incl = sd[t];
  if (i < n) row_ptr[i] = incl - v;
  if (t == 1023) partials[blockIdx.x] = incl;
}

__global__ __launch_bounds__(128) void scanB(int* partials, int nb) {
  __shared__ int sd[128];
  int t = threadIdx.x;
  int v = (t < nb) ? partials[t] : 0;
  sd[t] = v;
  __syncthreads();
  for (int off = 1; off < 128; off <<= 1) {
    int u = (t >= off) ? sd[t - off] : 0;
    __syncthreads();
    sd[t] += u;
    __syncthreads();
  }
  int incl = sd[t];
  partials[t] = incl - v;
  if (t == nb - 1) partials[255] = incl;
}

__global__ __launch_bounds__(1024) void scanC(int* row_ptr, const int* __restrict__ partials, int n) {
  int i = blockIdx.x * 1024 + threadIdx.x;
  if (i < n) row_ptr[i] += partials[blockIdx.x];
  if (i == 0) row_ptr[n] = partials[255];
}

__global__ __launch_bounds__(256) void fill_kernel(const int* __restrict__ ei,
    const float* __restrict__ ew, const float* __restrict__ dinv,
    const int* __restrict__ row_ptr, const int* __restrict__ rank,
    int2* __restrict__ epair, int E) {
  int e = blockIdx.x * 256 + threadIdx.x;
  if (e >= E) return;
  int s = ei[e], d = ei[E + e];
  float nw = dinv[s] * ew[e] * dinv[d];
  int p = row_ptr[d] + rank[e];
  epair[p] = make_int2(s, __float_as_int(nw));
}

// ---- aggregation: out[n] = sum_{e: dst=n} norm_e * xw[src_e] + dinv^2*xw[n] + b
template <int F, bool RELU, bool OUTF16>
__global__ __launch_bounds__(256) void agg_kernel(const unsigned short* __restrict__ xwh,
    const int* __restrict__ row_ptr, const int2* __restrict__ epair,
    const float* __restrict__ dinv, const float* __restrict__ bias,
    void* __restrict__ out, int Nn) {
  constexpr int LPN = F / 4;
  int t = blockIdx.x * 256 + threadIdx.x;
  int node = t / LPN;
  int lane = t % LPN;
  if (node >= Nn) return;
  const uint2* xh = (const uint2*)xwh;
  int start = row_ptr[node];
  int end = row_ptr[node + 1];
  float a0x = 0.f, a0y = 0.f, a0z = 0.f, a0w = 0.f;
  float a1x = 0.f, a1y = 0.f, a1z = 0.f, a1w = 0.f;
  int p = start;
  for (; p + 4 <= end; p += 4) {
    int2 e0 = epair[p];
    int2 e1 = epair[p + 1];
    int2 e2 = epair[p + 2];
    int2 e3 = epair[p + 3];
    uint2 u0 = xh[(size_t)e0.x * LPN + lane];
    uint2 u1 = xh[(size_t)e1.x * LPN + lane];
    uint2 u2 = xh[(size_t)e2.x * LPN + lane];
    uint2 u3 = xh[(size_t)e3.x * LPN + lane];
    float n0 = __int_as_float(e0.y), n1 = __int_as_float(e1.y);
    float n2 = __int_as_float(e2.y), n3 = __int_as_float(e3.y);
    float2 f0a = __half22float2(*(__half2*)&u0.x), f0b = __half22float2(*(__half2*)&u0.y);
    float2 f1a = __half22float2(*(__half2*)&u1.x), f1b = __half22float2(*(__half2*)&u1.y);
    float2 f2a = __half22float2(*(__half2*)&u2.x), f2b = __half22float2(*(__half2*)&u2.y);
    float2 f3a = __half22float2(*(__half2*)&u3.x), f3b = __half22float2(*(__half2*)&u3.y);
    a0x = fmaf(n0, f0a.x, a0x); a0y = fmaf(n0, f0a.y, a0y);
    a0z = fmaf(n0, f0b.x, a0z); a0w = fmaf(n0, f0b.y, a0w);
    a1x = fmaf(n1, f1a.x, a1x); a1y = fmaf(n1, f1a.y, a1y);
    a1z = fmaf(n1, f1b.x, a1z); a1w = fmaf(n1, f1b.y, a1w);
    a0x = fmaf(n2, f2a.x, a0x); a0y = fmaf(n2, f2a.y, a0y);
    a0z = fmaf(n2, f2b.x, a0z); a0w = fmaf(n2, f2b.y, a0w);
    a1x = fmaf(n3, f3a.x, a1x); a1y = fmaf(n3, f3a.y, a1y);
    a1z = fmaf(n3, f3b.x, a1z); a1w = fmaf(n3, f3b.y, a1w);
  }
  for (; p < end; ++p) {
    int2 pr = epair[p];
    float nw = __int_as_float(pr.y);
    uint2 u = xh[(size_t)pr.x * LPN + lane];
    float2 fa = __half22float2(*(__half2*)&u.x), fb = __half22float2(*(__half2*)&u.y);
    a0x = fmaf(nw, fa.x, a0x); a0y = fmaf(nw, fa.y, a0y);
    a0z = fmaf(nw, fb.x, a0z); a0w = fmaf(nw, fb.y, a0w);
  }
  float di = dinv[node];
  float sw = di * di;
  uint2 su = xh[(size_t)node * LPN + lane];
  float2 sa = __half22float2(*(__half2*)&su.x), sb = __half22float2(*(__half2*)&su.y);
  a0x = fmaf(sw, sa.x, a0x); a0y = fmaf(sw, sa.y, a0y);
  a0z = fmaf(sw, sb.x, a0z); a0w = fmaf(sw, sb.y, a0w);
  float4 b = ((const float4*)bias)[lane];
  float ox = a0x + a1x + b.x;
  float oy = a0y + a1y + b.y;
  float oz = a0z + a1z + b.z;
  float ow = a0w + a1w + b.w;
  if (RELU) {
    ox = fmaxf(ox, 0.f); oy = fmaxf(oy, 0.f);
    oz = fmaxf(oz, 0.f); ow = fmaxf(ow, 0.f);
  }
  if constexpr (OUTF16) {
    uint2 o;
    __half2 h0 = __float22half2_rn(make_float2(ox, oy));
    __half2 h1 = __float22half2_rn(make_float2(oz, ow));
    o.x = *reinterpret_cast<unsigned*>(&h0);
    o.y = *reinterpret_cast<unsigned*>(&h1);
    ((uint2*)out)[(size_t)node * LPN + lane] = o;
  } else {
    ((float4*)out)[(size_t)node * LPN + lane] = make_float4(ox, oy, oz, ow);
  }
}

// ---------------------------------------------------------------------------
extern "C" void kernel_launch(void* const* d_in, const int* in_sizes, int n_in,
                              void* d_out, int out_size, void* d_ws, size_t ws_size,
                              hipStream_t stream) {
  const float* x  = (const float*)d_in[0];
  const int*   ei = (const int*)d_in[1];     // int32, [2,E] flat
  const float* ew = (const float*)d_in[2];
  const float* W1 = (const float*)d_in[3];
  const float* b1 = (const float*)d_in[4];
  const float* W2 = (const float*)d_in[5];
  const float* b2 = (const float*)d_in[6];
  const float* W3 = (const float*)d_in[7];
  const float* b3 = (const float*)d_in[8];

  const int N = in_sizes[0] / 128;           // 100000
  const int E = in_sizes[2];                 // 1600000

  // workspace carve (256B aligned)
  char* ws = (char*)d_ws;
  size_t off = 0;
  auto carve = [&](size_t bytes) -> void* {
    void* p = ws + off;
    off += (bytes + 255) & ~(size_t)255;
    return p;
  };
  unsigned long long* packed = (unsigned long long*)carve((size_t)N * 8);
  int*   rank    = (int*)carve((size_t)E * 4);
  float* dinv    = (float*)carve((size_t)N * 4);
  int*   row_ptr = (int*)carve((size_t)(N + 1) * 4);
  int*   parts   = (int*)carve(256 * 4);
  int2*  epair   = (int2*)carve((size_t)E * 8);
  unsigned short* bufH = (unsigned short*)carve((size_t)N * 128 * 2);  // fp16 xw
  unsigned short* bufI = (unsigned short*)carve((size_t)N * 128 * 2);  // fp16 h
  unsigned short* WT1g = (unsigned short*)carve(2 * 128 * 128 * 2);    // frag-layout W1
  (void)ws_size; (void)n_in; (void)out_size;

  const int nThreads = 256;
  int gN  = (N + nThreads - 1) / nThreads;
  int gE  = (E + nThreads - 1) / nThreads;
  int nb  = (N + 1023) / 1024;               // scan blocks (98)
  const int gMM = (N + 63) / 64;             // 1563 MFMA blocks (64 rows each)
  int gAgg128 = (N * 32 + nThreads - 1) / nThreads;
  int gAgg64  = (N * 16 + nThreads - 1) / nThreads;

  // --- D0: zero histogram + convert W1 to fragment layout (tiny) ---
  hipMemsetAsync(packed, 0, (size_t)N * 8, stream);
  prep_w1_kernel<<<1, nThreads, 0, stream>>>(W1, WT1g);

  // --- D1: edge_pass (first) co-dispatched with LDS-free layer-1 GEMM ---
  pre_gemm_fused_kernel<<<gE + gMM, nThreads, 0, stream>>>(
      x, WT1g, bufH, N, ei, ew, packed, rank, E, gE);

  // --- graph preprocessing tail ---
  dinv_kernel<<<gN, nThreads, 0, stream>>>(packed, dinv, N);
  scanA<<<nb, 1024, 0, stream>>>(packed, row_ptr, parts, N);
  scanB<<<1, 128, 0, stream>>>(parts, nb);
  scanC<<<nb, 1024, 0, stream>>>(row_ptr, parts, N);
  fill_kernel<<<gE, nThreads, 0, stream>>>(ei, ew, dinv, row_ptr, rank, epair, E);

  // --- layer 1 aggregate -> fp16 h1 ---
  agg_kernel<128, true, true><<<gAgg128, nThreads, 0, stream>>>(bufH, row_ptr, epair, dinv, b1, bufI, N);

  // --- layer 2: gemm (fp16 A) -> bufH; agg -> fp16 h2 ---
  gemm_mfma_kernel<128><<<gMM, nThreads, 0, stream>>>(bufI, W2, bufH, N);
  agg_kernel<128, true, true><<<gAgg128, nThreads, 0, stream>>>(bufH, row_ptr, epair, dinv, b2, bufI, N);

  // --- layer 3: gemm 64-wide (fp16 A) -> bufH; agg -> fp32 d_out ---
  gemm_mfma_kernel<64><<<gMM, nThreads, 0, stream>>>(bufI, W3, bufH, N);
  agg_kernel<64, false, false><<<gAgg64, nThreads, 0, stream>>>(bufH, row_ptr, epair, dinv, b3, d_out, N);
}

// Round 12
// 352.110 us; speedup vs baseline: 1.0398x; 1.0398x over previous
//
#include <hip/hip_runtime.h>
#include <hip/hip_fp16.h>
#include <math.h>

// ---------------------------------------------------------------------------
// GCN 3-layer forward on MI355X.
// Round 11 change: LDS-free fused gemm regressed (per-lane W-frag gathers
// tripled VMEM ops: VALU 6%, 121us). Revert to LDS-staged gemm in the fused
// kernel but with 32KB LDS (two 64-col slices, grid 2x) so co-resident edge
// blocks keep ~20 waves/CU (round-10's 64KB gave them only 8). Edge blocks
// first. Layers 2/3 keep full-width LDS gemm.
// ---------------------------------------------------------------------------

typedef __bf16 bf16x8 __attribute__((ext_vector_type(8)));
typedef float f32x4 __attribute__((ext_vector_type(4)));

union BF8 {
  unsigned short u[8];
  uint4 q;
  bf16x8 v;
};

__device__ __forceinline__ unsigned short rne_bf16(float f) {
  unsigned u = __float_as_uint(f);
  u += 0x7fff + ((u >> 16) & 1);
  return (unsigned short)(u >> 16);
}
__device__ __forceinline__ float bf16_to_f(unsigned short h) {
  return __uint_as_float((unsigned)h << 16);
}

// ---- 64-col-slice MFMA gemm body (32KB LDS): Ch[:,col0:col0+64] ------------
// fp32 A; W row-stride ldw; 3-term split-bf16; 1-step A prefetch.
__device__ __forceinline__ void gemm_body_slice(const float* __restrict__ A,
    const float* __restrict__ W, int ldw, int col0,
    unsigned short* __restrict__ Ch, int ldc, int M, int bid) {
  constexpr int NF = 4;
  __shared__ __align__(16) unsigned short WT[2][64][128];
  const int t = threadIdx.x;
#pragma unroll
  for (int it = 0; it < 4; ++it) {
    int n = t & 63;
    int kc = it * 4 + (t >> 6);
    int k0 = kc * 8;
    BF8 hh, ll;
#pragma unroll
    for (int j = 0; j < 8; ++j) {
      float w = W[(size_t)(k0 + j) * ldw + col0 + n];
      unsigned short hb = rne_bf16(w);
      hh.u[j] = hb;
      ll.u[j] = rne_bf16(w - bf16_to_f(hb));
    }
    int kk = k0 ^ ((n & 7) << 3);
    *(uint4*)&WT[0][n][kk] = hh.q;
    *(uint4*)&WT[1][n][kk] = ll.q;
  }
  __syncthreads();

  const int wv = t >> 6;
  const int l = t & 63;
  const int lr = l & 15;
  const int lg = l >> 4;
  const int arow_i = bid * 64 + wv * 16 + lr;
  const bool rv = arow_i < M;
  const float* arow = A + (size_t)arow_i * 128;

  f32x4 acc[NF] = {};
  float4 p0 = make_float4(0.f, 0.f, 0.f, 0.f), p1 = p0;
  if (rv) {
    p0 = *(const float4*)&arow[lg * 8];
    p1 = *(const float4*)&arow[lg * 8 + 4];
  }
#pragma unroll 1
  for (int ks = 0; ks < 4; ++ks) {
    int nkb = ((ks < 3) ? (ks + 1) * 32 : ks * 32) + lg * 8;
    float4 q0 = make_float4(0.f, 0.f, 0.f, 0.f), q1 = q0;
    if (rv) {
      q0 = *(const float4*)&arow[nkb];
      q1 = *(const float4*)&arow[nkb + 4];
    }
    float av[8] = {p0.x, p0.y, p0.z, p0.w, p1.x, p1.y, p1.z, p1.w};
    BF8 ah, al;
#pragma unroll
    for (int j = 0; j < 8; ++j) {
      unsigned short hb = rne_bf16(av[j]);
      ah.u[j] = hb;
      al.u[j] = rne_bf16(av[j] - bf16_to_f(hb));
    }
    int kidx = ks * 32 + lg * 8;
    BF8 bh[NF], bl[NF];
#pragma unroll
    for (int nf = 0; nf < NF; ++nf) {
      int n = nf * 16 + lr;
      int kk = kidx ^ ((n & 7) << 3);
      bh[nf].q = *(const uint4*)&WT[0][n][kk];
      bl[nf].q = *(const uint4*)&WT[1][n][kk];
    }
#pragma unroll
    for (int nf = 0; nf < NF; ++nf) {
      acc[nf] = __builtin_amdgcn_mfma_f32_16x16x32_bf16(ah.v, bh[nf].v, acc[nf], 0, 0, 0);
      acc[nf] = __builtin_amdgcn_mfma_f32_16x16x32_bf16(al.v, bh[nf].v, acc[nf], 0, 0, 0);
      acc[nf] = __builtin_amdgcn_mfma_f32_16x16x32_bf16(ah.v, bl[nf].v, acc[nf], 0, 0, 0);
    }
    p0 = q0; p1 = q1;
  }
  const int orow0 = bid * 64 + wv * 16 + lg * 4;
#pragma unroll
  for (int j = 0; j < 4; ++j) {
    int orow = orow0 + j;
    if (orow < M) {
      unsigned short* hr = Ch + (size_t)orow * ldc + col0;
#pragma unroll
      for (int nf = 0; nf < NF; ++nf)
        hr[nf * 16 + lr] = __half_as_ushort(__float2half(acc[nf][j]));
    }
  }
}

// fused dispatch: blocks [0,edgeBlocks) = edge_pass (atomics start at t=0);
// rest = layer-1 GEMM in 64-col slices (32KB LDS -> edge keeps ~20 waves/CU).
__global__ __launch_bounds__(256) void pre_gemm_fused_kernel(
    const float* __restrict__ x, const float* __restrict__ W1,
    unsigned short* __restrict__ Ch, int M,
    const int* __restrict__ ei, const float* __restrict__ ew,
    unsigned long long* __restrict__ packed, int* __restrict__ rank,
    int E, int edgeBlocks) {
  if ((int)blockIdx.x < edgeBlocks) {
    int e = blockIdx.x * 256 + threadIdx.x;
    if (e >= E) return;
    int d = ei[E + e];
    unsigned wfix = (unsigned)__float2uint_rn(ew[e] * 16777216.0f);  // Q24
    unsigned long long inc = (1ULL << 32) | (unsigned long long)wfix;
    unsigned long long old = atomicAdd(&packed[d], inc);
    rank[e] = (int)(old >> 32);
  } else {
    int g = blockIdx.x - edgeBlocks;
    gemm_body_slice(x, W1, 128, (g & 1) * 64, Ch, 128, M, g >> 1);
  }
}

// ---- LDS-staged full-width MFMA gemm (layers 2,3; fp16 A input) ------------
template <int NCOL>
__global__ __launch_bounds__(256) void gemm_mfma_kernel(
    const unsigned short* __restrict__ Ah, const float* __restrict__ W,
    unsigned short* __restrict__ Ch, int M) {
  constexpr int NF = NCOL / 16;
  __shared__ __align__(16) unsigned short WT[2][NCOL][128];
  const int t = threadIdx.x;
  constexpr int KC_PER_IT = 256 / NCOL;
#pragma unroll
  for (int it = 0; it < 16 / KC_PER_IT; ++it) {
    int n = t % NCOL;
    int kc = it * KC_PER_IT + t / NCOL;
    int k0 = kc * 8;
    BF8 hh, ll;
#pragma unroll
    for (int j = 0; j < 8; ++j) {
      float w = W[(size_t)(k0 + j) * NCOL + n];
      unsigned short hb = rne_bf16(w);
      hh.u[j] = hb;
      ll.u[j] = rne_bf16(w - bf16_to_f(hb));
    }
    int kk = k0 ^ ((n & 7) << 3);
    *(uint4*)&WT[0][n][kk] = hh.q;
    *(uint4*)&WT[1][n][kk] = ll.q;
  }
  __syncthreads();

  const int wv = t >> 6;
  const int l = t & 63;
  const int lr = l & 15;
  const int lg = l >> 4;
  const int arow_i = blockIdx.x * 64 + wv * 16 + lr;
  const bool rv = arow_i < M;
  const unsigned short* arowh = Ah + (size_t)arow_i * 128;

  f32x4 acc[NF] = {};
  uint4 ph = make_uint4(0, 0, 0, 0);
  if (rv) ph = *(const uint4*)&arowh[lg * 8];
#pragma unroll 1
  for (int ks = 0; ks < 4; ++ks) {
    int nkb = ((ks < 3) ? (ks + 1) * 32 : ks * 32) + lg * 8;
    uint4 qh = make_uint4(0, 0, 0, 0);
    if (rv) qh = *(const uint4*)&arowh[nkb];
    float av[8];
    {
      union { uint4 q; __half2 h2[4]; } uu;
      uu.q = ph;
#pragma unroll
      for (int j = 0; j < 4; ++j) {
        float2 f = __half22float2(uu.h2[j]);
        av[j * 2] = f.x; av[j * 2 + 1] = f.y;
      }
    }
    BF8 ah, al;
#pragma unroll
    for (int j = 0; j < 8; ++j) {
      unsigned short hb = rne_bf16(av[j]);
      ah.u[j] = hb;
      al.u[j] = rne_bf16(av[j] - bf16_to_f(hb));
    }
    int kidx = ks * 32 + lg * 8;
    BF8 bh[NF], bl[NF];
#pragma unroll
    for (int nf = 0; nf < NF; ++nf) {
      int n = nf * 16 + lr;
      int kk = kidx ^ ((n & 7) << 3);
      bh[nf].q = *(const uint4*)&WT[0][n][kk];
      bl[nf].q = *(const uint4*)&WT[1][n][kk];
    }
#pragma unroll
    for (int nf = 0; nf < NF; ++nf) {
      acc[nf] = __builtin_amdgcn_mfma_f32_16x16x32_bf16(ah.v, bh[nf].v, acc[nf], 0, 0, 0);
      acc[nf] = __builtin_amdgcn_mfma_f32_16x16x32_bf16(al.v, bh[nf].v, acc[nf], 0, 0, 0);
      acc[nf] = __builtin_amdgcn_mfma_f32_16x16x32_bf16(ah.v, bl[nf].v, acc[nf], 0, 0, 0);
    }
    ph = qh;
  }
  const int orow0 = blockIdx.x * 64 + wv * 16 + lg * 4;
#pragma unroll
  for (int j = 0; j < 4; ++j) {
    int orow = orow0 + j;
    if (orow < M) {
      unsigned short* hr = Ch + (size_t)orow * NCOL;
#pragma unroll
      for (int nf = 0; nf < NF; ++nf)
        hr[nf * 16 + lr] = __half_as_ushort(__float2half(acc[nf][j]));
    }
  }
}

__global__ __launch_bounds__(256) void dinv_kernel(const unsigned long long* __restrict__ packed,
    float* __restrict__ dinv, int n) {
  int i = blockIdx.x * 256 + threadIdx.x;
  if (i >= n) return;
  float deg = 1.0f + (float)(unsigned)(packed[i] & 0xffffffffULL) * (1.0f / 16777216.0f);
  dinv[i] = 1.0f / sqrtf(deg);
}

// ---- 3-kernel exclusive scan of counts (hi32 of packed) -> row_ptr ---------
__global__ __launch_bounds__(1024) void scanA(const unsigned long long* __restrict__ packed,
    int* __restrict__ row_ptr, int* __restrict__ partials, int n) {
  __shared__ int sd[1024];
  int t = threadIdx.x;
  int i = blockIdx.x * 1024 + t;
  int v = (i < n) ? (int)(packed[i] >> 32) : 0;
  sd[t] = v;
  __syncthreads();
  for (int off = 1; off < 1024; off <<= 1) {
    int u = (t >= off) ? sd[t - off] : 0;
    __syncthreads();
    sd[t] += u;
    __syncthreads();
  }
  int incl = sd[t];
  if (i < n) row_ptr[i] = incl - v;
  if (t == 1023) partials[blockIdx.x] = incl;
}

__global__ __launch_bounds__(128) void scanB(int* partials, int nb) {
  __shared__ int sd[128];
  int t = threadIdx.x;
  int v = (t < nb) ? partials[t] : 0;
  sd[t] = v;
  __syncthreads();
  for (int off = 1; off < 128; off <<= 1) {
    int u = (t >= off) ? sd[t - off] : 0;
    __syncthreads();
    sd[t] += u;
    __syncthreads();
  }
  int incl = sd[t];
  partials[t] = incl - v;
  if (t == nb - 1) partials[255] = incl;
}

__global__ __launch_bounds__(1024) void scanC(int* row_ptr, const int* __restrict__ partials, int n) {
  int i = blockIdx.x * 1024 + threadIdx.x;
  if (i < n) row_ptr[i] += partials[blockIdx.x];
  if (i == 0) row_ptr[n] = partials[255];
}

__global__ __launch_bounds__(256) void fill_kernel(const int* __restrict__ ei,
    const float* __restrict__ ew, const float* __restrict__ dinv,
    const int* __restrict__ row_ptr, const int* __restrict__ rank,
    int2* __restrict__ epair, int E) {
  int e = blockIdx.x * 256 + threadIdx.x;
  if (e >= E) return;
  int s = ei[e], d = ei[E + e];
  float nw = dinv[s] * ew[e] * dinv[d];
  int p = row_ptr[d] + rank[e];
  epair[p] = make_int2(s, __float_as_int(nw));
}

// ---- aggregation: out[n] = sum_{e: dst=n} norm_e * xw[src_e] + dinv^2*xw[n] + b
template <int F, bool RELU, bool OUTF16>
__global__ __launch_bounds__(256) void agg_kernel(const unsigned short* __restrict__ xwh,
    const int* __restrict__ row_ptr, const int2* __restrict__ epair,
    const float* __restrict__ dinv, const float* __restrict__ bias,
    void* __restrict__ out, int Nn) {
  constexpr int LPN = F / 4;
  int t = blockIdx.x * 256 + threadIdx.x;
  int node = t / LPN;
  int lane = t % LPN;
  if (node >= Nn) return;
  const uint2* xh = (const uint2*)xwh;
  int start = row_ptr[node];
  int end = row_ptr[node + 1];
  float a0x = 0.f, a0y = 0.f, a0z = 0.f, a0w = 0.f;
  float a1x = 0.f, a1y = 0.f, a1z = 0.f, a1w = 0.f;
  int p = start;
  for (; p + 4 <= end; p += 4) {
    int2 e0 = epair[p];
    int2 e1 = epair[p + 1];
    int2 e2 = epair[p + 2];
    int2 e3 = epair[p + 3];
    uint2 u0 = xh[(size_t)e0.x * LPN + lane];
    uint2 u1 = xh[(size_t)e1.x * LPN + lane];
    uint2 u2 = xh[(size_t)e2.x * LPN + lane];
    uint2 u3 = xh[(size_t)e3.x * LPN + lane];
    float n0 = __int_as_float(e0.y), n1 = __int_as_float(e1.y);
    float n2 = __int_as_float(e2.y), n3 = __int_as_float(e3.y);
    float2 f0a = __half22float2(*(__half2*)&u0.x), f0b = __half22float2(*(__half2*)&u0.y);
    float2 f1a = __half22float2(*(__half2*)&u1.x), f1b = __half22float2(*(__half2*)&u1.y);
    float2 f2a = __half22float2(*(__half2*)&u2.x), f2b = __half22float2(*(__half2*)&u2.y);
    float2 f3a = __half22float2(*(__half2*)&u3.x), f3b = __half22float2(*(__half2*)&u3.y);
    a0x = fmaf(n0, f0a.x, a0x); a0y = fmaf(n0, f0a.y, a0y);
    a0z = fmaf(n0, f0b.x, a0z); a0w = fmaf(n0, f0b.y, a0w);
    a1x = fmaf(n1, f1a.x, a1x); a1y = fmaf(n1, f1a.y, a1y);
    a1z = fmaf(n1, f1b.x, a1z); a1w = fmaf(n1, f1b.y, a1w);
    a0x = fmaf(n2, f2a.x, a0x); a0y = fmaf(n2, f2a.y, a0y);
    a0z = fmaf(n2, f2b.x, a0z); a0w = fmaf(n2, f2b.y, a0w);
    a1x = fmaf(n3, f3a.x, a1x); a1y = fmaf(n3, f3a.y, a1y);
    a1z = fmaf(n3, f3b.x, a1z); a1w = fmaf(n3, f3b.y, a1w);
  }
  for (; p < end; ++p) {
    int2 pr = epair[p];
    float nw = __int_as_float(pr.y);
    uint2 u = xh[(size_t)pr.x * LPN + lane];
    float2 fa = __half22float2(*(__half2*)&u.x), fb = __half22float2(*(__half2*)&u.y);
    a0x = fmaf(nw, fa.x, a0x); a0y = fmaf(nw, fa.y, a0y);
    a0z = fmaf(nw, fb.x, a0z); a0w = fmaf(nw, fb.y, a0w);
  }
  float di = dinv[node];
  float sw = di * di;
  uint2 su = xh[(size_t)node * LPN + lane];
  float2 sa = __half22float2(*(__half2*)&su.x), sb = __half22float2(*(__half2*)&su.y);
  a0x = fmaf(sw, sa.x, a0x); a0y = fmaf(sw, sa.y, a0y);
  a0z = fmaf(sw, sb.x, a0z); a0w = fmaf(sw, sb.y, a0w);
  float4 b = ((const float4*)bias)[lane];
  float ox = a0x + a1x + b.x;
  float oy = a0y + a1y + b.y;
  float oz = a0z + a1z + b.z;
  float ow = a0w + a1w + b.w;
  if (RELU) {
    ox = fmaxf(ox, 0.f); oy = fmaxf(oy, 0.f);
    oz = fmaxf(oz, 0.f); ow = fmaxf(ow, 0.f);
  }
  if constexpr (OUTF16) {
    uint2 o;
    __half2 h0 = __float22half2_rn(make_float2(ox, oy));
    __half2 h1 = __float22half2_rn(make_float2(oz, ow));
    o.x = *reinterpret_cast<unsigned*>(&h0);
    o.y = *reinterpret_cast<unsigned*>(&h1);
    ((uint2*)out)[(size_t)node * LPN + lane] = o;
  } else {
    ((float4*)out)[(size_t)node * LPN + lane] = make_float4(ox, oy, oz, ow);
  }
}

// ---------------------------------------------------------------------------
extern "C" void kernel_launch(void* const* d_in, const int* in_sizes, int n_in,
                              void* d_out, int out_size, void* d_ws, size_t ws_size,
                              hipStream_t stream) {
  const float* x  = (const float*)d_in[0];
  const int*   ei = (const int*)d_in[1];     // int32, [2,E] flat
  const float* ew = (const float*)d_in[2];
  const float* W1 = (const float*)d_in[3];
  const float* b1 = (const float*)d_in[4];
  const float* W2 = (const float*)d_in[5];
  const float* b2 = (const float*)d_in[6];
  const float* W3 = (const float*)d_in[7];
  const float* b3 = (const float*)d_in[8];

  const int N = in_sizes[0] / 128;           // 100000
  const int E = in_sizes[2];                 // 1600000

  // workspace carve (256B aligned)
  char* ws = (char*)d_ws;
  size_t off = 0;
  auto carve = [&](size_t bytes) -> void* {
    void* p = ws + off;
    off += (bytes + 255) & ~(size_t)255;
    return p;
  };
  unsigned long long* packed = (unsigned long long*)carve((size_t)N * 8);
  int*   rank    = (int*)carve((size_t)E * 4);
  float* dinv    = (float*)carve((size_t)N * 4);
  int*   row_ptr = (int*)carve((size_t)(N + 1) * 4);
  int*   parts   = (int*)carve(256 * 4);
  int2*  epair   = (int2*)carve((size_t)E * 8);
  unsigned short* bufH = (unsigned short*)carve((size_t)N * 128 * 2);  // fp16 xw
  unsigned short* bufI = (unsigned short*)carve((size_t)N * 128 * 2);  // fp16 h
  (void)ws_size; (void)n_in; (void)out_size;

  const int nThreads = 256;
  int gN  = (N + nThreads - 1) / nThreads;
  int gE  = (E + nThreads - 1) / nThreads;
  int nb  = (N + 1023) / 1024;               // scan blocks (98)
  const int gMM = (N + 63) / 64;             // 1563 MFMA row-blocks
  int gAgg128 = (N * 32 + nThreads - 1) / nThreads;
  int gAgg64  = (N * 16 + nThreads - 1) / nThreads;

  // --- D1: edge_pass (first) co-dispatched with 32KB-LDS layer-1 GEMM ---
  hipMemsetAsync(packed, 0, (size_t)N * 8, stream);
  pre_gemm_fused_kernel<<<gE + 2 * gMM, nThreads, 0, stream>>>(
      x, W1, bufH, N, ei, ew, packed, rank, E, gE);

  // --- graph preprocessing tail ---
  dinv_kernel<<<gN, nThreads, 0, stream>>>(packed, dinv, N);
  scanA<<<nb, 1024, 0, stream>>>(packed, row_ptr, parts, N);
  scanB<<<1, 128, 0, stream>>>(parts, nb);
  scanC<<<nb, 1024, 0, stream>>>(row_ptr, parts, N);
  fill_kernel<<<gE, nThreads, 0, stream>>>(ei, ew, dinv, row_ptr, rank, epair, E);

  // --- layer 1 aggregate -> fp16 h1 ---
  agg_kernel<128, true, true><<<gAgg128, nThreads, 0, stream>>>(bufH, row_ptr, epair, dinv, b1, bufI, N);

  // --- layer 2: gemm (fp16 A) -> bufH; agg -> fp16 h2 ---
  gemm_mfma_kernel<128><<<gMM, nThreads, 0, stream>>>(bufI, W2, bufH, N);
  agg_kernel<128, true, true><<<gAgg128, nThreads, 0, stream>>>(bufH, row_ptr, epair, dinv, b2, bufI, N);

  // --- layer 3: gemm 64-wide (fp16 A) -> bufH; agg -> fp32 d_out ---
  gemm_mfma_kernel<64><<<gMM, nThreads, 0, stream>>>(bufI, W3, bufH, N);
  agg_kernel<64, false, false><<<gAgg64, nThreads, 0, stream>>>(bufH, row_ptr, epair, dinv, b3, d_out, N);
}

// Round 13
// 341.416 us; speedup vs baseline: 1.0723x; 1.0313x over previous
//
#include <hip/hip_runtime.h>
#include <hip/hip_fp16.h>
#include <math.h>

// ---------------------------------------------------------------------------
// GCN 3-layer forward on MI355X.
// Round 12 change: fusion variants mapped (105/112/121 vs 108 serial) — keep
// 32KB-LDS fused. New: agg gathers widened to 16 lanes/node x 16B uint4
// (8 halves per lane) -> VMEM op count halved at same bytes; dinv folded
// into scanA (one fewer dispatch).
// ---------------------------------------------------------------------------

typedef __bf16 bf16x8 __attribute__((ext_vector_type(8)));
typedef float f32x4 __attribute__((ext_vector_type(4)));

union BF8 {
  unsigned short u[8];
  uint4 q;
  bf16x8 v;
};

union H8 {
  uint4 q;
  __half2 h2[4];
};

__device__ __forceinline__ unsigned short rne_bf16(float f) {
  unsigned u = __float_as_uint(f);
  u += 0x7fff + ((u >> 16) & 1);
  return (unsigned short)(u >> 16);
}
__device__ __forceinline__ float bf16_to_f(unsigned short h) {
  return __uint_as_float((unsigned)h << 16);
}

// ---- 64-col-slice MFMA gemm body (32KB LDS): Ch[:,col0:col0+64] ------------
__device__ __forceinline__ void gemm_body_slice(const float* __restrict__ A,
    const float* __restrict__ W, int ldw, int col0,
    unsigned short* __restrict__ Ch, int ldc, int M, int bid) {
  constexpr int NF = 4;
  __shared__ __align__(16) unsigned short WT[2][64][128];
  const int t = threadIdx.x;
#pragma unroll
  for (int it = 0; it < 4; ++it) {
    int n = t & 63;
    int kc = it * 4 + (t >> 6);
    int k0 = kc * 8;
    BF8 hh, ll;
#pragma unroll
    for (int j = 0; j < 8; ++j) {
      float w = W[(size_t)(k0 + j) * ldw + col0 + n];
      unsigned short hb = rne_bf16(w);
      hh.u[j] = hb;
      ll.u[j] = rne_bf16(w - bf16_to_f(hb));
    }
    int kk = k0 ^ ((n & 7) << 3);
    *(uint4*)&WT[0][n][kk] = hh.q;
    *(uint4*)&WT[1][n][kk] = ll.q;
  }
  __syncthreads();

  const int wv = t >> 6;
  const int l = t & 63;
  const int lr = l & 15;
  const int lg = l >> 4;
  const int arow_i = bid * 64 + wv * 16 + lr;
  const bool rv = arow_i < M;
  const float* arow = A + (size_t)arow_i * 128;

  f32x4 acc[NF] = {};
  float4 p0 = make_float4(0.f, 0.f, 0.f, 0.f), p1 = p0;
  if (rv) {
    p0 = *(const float4*)&arow[lg * 8];
    p1 = *(const float4*)&arow[lg * 8 + 4];
  }
#pragma unroll 1
  for (int ks = 0; ks < 4; ++ks) {
    int nkb = ((ks < 3) ? (ks + 1) * 32 : ks * 32) + lg * 8;
    float4 q0 = make_float4(0.f, 0.f, 0.f, 0.f), q1 = q0;
    if (rv) {
      q0 = *(const float4*)&arow[nkb];
      q1 = *(const float4*)&arow[nkb + 4];
    }
    float av[8] = {p0.x, p0.y, p0.z, p0.w, p1.x, p1.y, p1.z, p1.w};
    BF8 ah, al;
#pragma unroll
    for (int j = 0; j < 8; ++j) {
      unsigned short hb = rne_bf16(av[j]);
      ah.u[j] = hb;
      al.u[j] = rne_bf16(av[j] - bf16_to_f(hb));
    }
    int kidx = ks * 32 + lg * 8;
    BF8 bh[NF], bl[NF];
#pragma unroll
    for (int nf = 0; nf < NF; ++nf) {
      int n = nf * 16 + lr;
      int kk = kidx ^ ((n & 7) << 3);
      bh[nf].q = *(const uint4*)&WT[0][n][kk];
      bl[nf].q = *(const uint4*)&WT[1][n][kk];
    }
#pragma unroll
    for (int nf = 0; nf < NF; ++nf) {
      acc[nf] = __builtin_amdgcn_mfma_f32_16x16x32_bf16(ah.v, bh[nf].v, acc[nf], 0, 0, 0);
      acc[nf] = __builtin_amdgcn_mfma_f32_16x16x32_bf16(al.v, bh[nf].v, acc[nf], 0, 0, 0);
      acc[nf] = __builtin_amdgcn_mfma_f32_16x16x32_bf16(ah.v, bl[nf].v, acc[nf], 0, 0, 0);
    }
    p0 = q0; p1 = q1;
  }
  const int orow0 = bid * 64 + wv * 16 + lg * 4;
#pragma unroll
  for (int j = 0; j < 4; ++j) {
    int orow = orow0 + j;
    if (orow < M) {
      unsigned short* hr = Ch + (size_t)orow * ldc + col0;
#pragma unroll
      for (int nf = 0; nf < NF; ++nf)
        hr[nf * 16 + lr] = __half_as_ushort(__float2half(acc[nf][j]));
    }
  }
}

// fused dispatch: blocks [0,edgeBlocks) = edge_pass; rest = layer-1 GEMM.
__global__ __launch_bounds__(256) void pre_gemm_fused_kernel(
    const float* __restrict__ x, const float* __restrict__ W1,
    unsigned short* __restrict__ Ch, int M,
    const int* __restrict__ ei, const float* __restrict__ ew,
    unsigned long long* __restrict__ packed, int* __restrict__ rank,
    int E, int edgeBlocks) {
  if ((int)blockIdx.x < edgeBlocks) {
    int e = blockIdx.x * 256 + threadIdx.x;
    if (e >= E) return;
    int d = ei[E + e];
    unsigned wfix = (unsigned)__float2uint_rn(ew[e] * 16777216.0f);  // Q24
    unsigned long long inc = (1ULL << 32) | (unsigned long long)wfix;
    unsigned long long old = atomicAdd(&packed[d], inc);
    rank[e] = (int)(old >> 32);
  } else {
    int g = blockIdx.x - edgeBlocks;
    gemm_body_slice(x, W1, 128, (g & 1) * 64, Ch, 128, M, g >> 1);
  }
}

// ---- LDS-staged full-width MFMA gemm (layers 2,3; fp16 A input) ------------
template <int NCOL>
__global__ __launch_bounds__(256) void gemm_mfma_kernel(
    const unsigned short* __restrict__ Ah, const float* __restrict__ W,
    unsigned short* __restrict__ Ch, int M) {
  constexpr int NF = NCOL / 16;
  __shared__ __align__(16) unsigned short WT[2][NCOL][128];
  const int t = threadIdx.x;
  constexpr int KC_PER_IT = 256 / NCOL;
#pragma unroll
  for (int it = 0; it < 16 / KC_PER_IT; ++it) {
    int n = t % NCOL;
    int kc = it * KC_PER_IT + t / NCOL;
    int k0 = kc * 8;
    BF8 hh, ll;
#pragma unroll
    for (int j = 0; j < 8; ++j) {
      float w = W[(size_t)(k0 + j) * NCOL + n];
      unsigned short hb = rne_bf16(w);
      hh.u[j] = hb;
      ll.u[j] = rne_bf16(w - bf16_to_f(hb));
    }
    int kk = k0 ^ ((n & 7) << 3);
    *(uint4*)&WT[0][n][kk] = hh.q;
    *(uint4*)&WT[1][n][kk] = ll.q;
  }
  __syncthreads();

  const int wv = t >> 6;
  const int l = t & 63;
  const int lr = l & 15;
  const int lg = l >> 4;
  const int arow_i = blockIdx.x * 64 + wv * 16 + lr;
  const bool rv = arow_i < M;
  const unsigned short* arowh = Ah + (size_t)arow_i * 128;

  f32x4 acc[NF] = {};
  uint4 ph = make_uint4(0, 0, 0, 0);
  if (rv) ph = *(const uint4*)&arowh[lg * 8];
#pragma unroll 1
  for (int ks = 0; ks < 4; ++ks) {
    int nkb = ((ks < 3) ? (ks + 1) * 32 : ks * 32) + lg * 8;
    uint4 qh = make_uint4(0, 0, 0, 0);
    if (rv) qh = *(const uint4*)&arowh[nkb];
    float av[8];
    {
      H8 uu; uu.q = ph;
#pragma unroll
      for (int j = 0; j < 4; ++j) {
        float2 f = __half22float2(uu.h2[j]);
        av[j * 2] = f.x; av[j * 2 + 1] = f.y;
      }
    }
    BF8 ah, al;
#pragma unroll
    for (int j = 0; j < 8; ++j) {
      unsigned short hb = rne_bf16(av[j]);
      ah.u[j] = hb;
      al.u[j] = rne_bf16(av[j] - bf16_to_f(hb));
    }
    int kidx = ks * 32 + lg * 8;
    BF8 bh[NF], bl[NF];
#pragma unroll
    for (int nf = 0; nf < NF; ++nf) {
      int n = nf * 16 + lr;
      int kk = kidx ^ ((n & 7) << 3);
      bh[nf].q = *(const uint4*)&WT[0][n][kk];
      bl[nf].q = *(const uint4*)&WT[1][n][kk];
    }
#pragma unroll
    for (int nf = 0; nf < NF; ++nf) {
      acc[nf] = __builtin_amdgcn_mfma_f32_16x16x32_bf16(ah.v, bh[nf].v, acc[nf], 0, 0, 0);
      acc[nf] = __builtin_amdgcn_mfma_f32_16x16x32_bf16(al.v, bh[nf].v, acc[nf], 0, 0, 0);
      acc[nf] = __builtin_amdgcn_mfma_f32_16x16x32_bf16(ah.v, bl[nf].v, acc[nf], 0, 0, 0);
    }
    ph = qh;
  }
  const int orow0 = blockIdx.x * 64 + wv * 16 + lg * 4;
#pragma unroll
  for (int j = 0; j < 4; ++j) {
    int orow = orow0 + j;
    if (orow < M) {
      unsigned short* hr = Ch + (size_t)orow * NCOL;
#pragma unroll
      for (int nf = 0; nf < NF; ++nf)
        hr[nf * 16 + lr] = __half_as_ushort(__float2half(acc[nf][j]));
    }
  }
}

// ---- scanA with fused dinv: exclusive scan of counts + dinv[i] -------------
__global__ __launch_bounds__(1024) void scanA(const unsigned long long* __restrict__ packed,
    int* __restrict__ row_ptr, int* __restrict__ partials,
    float* __restrict__ dinv, int n) {
  __shared__ int sd[1024];
  int t = threadIdx.x;
  int i = blockIdx.x * 1024 + t;
  unsigned long long pv = (i < n) ? packed[i] : 0ULL;
  int v = (int)(pv >> 32);
  if (i < n) {
    float deg = 1.0f + (float)(unsigned)(pv & 0xffffffffULL) * (1.0f / 16777216.0f);
    dinv[i] = 1.0f / sqrtf(deg);
  }
  sd[t] = v;
  __syncthreads();
  for (int off = 1; off < 1024; off <<= 1) {
    int u = (t >= off) ? sd[t - off] : 0;
    __syncthreads();
    sd[t] += u;
    __syncthreads();
  }
  int incl = sd[t];
  if (i < n) row_ptr[i] = incl - v;
  if (t == 1023) partials[blockIdx.x] = incl;
}

__global__ __launch_bounds__(128) void scanB(int* partials, int nb) {
  __shared__ int sd[128];
  int t = threadIdx.x;
  int v = (t < nb) ? partials[t] : 0;
  sd[t] = v;
  __syncthreads();
  for (int off = 1; off < 128; off <<= 1) {
    int u = (t >= off) ? sd[t - off] : 0;
    __syncthreads();
    sd[t] += u;
    __syncthreads();
  }
  int incl = sd[t];
  partials[t] = incl - v;
  if (t == nb - 1) partials[255] = incl;
}

__global__ __launch_bounds__(1024) void scanC(int* row_ptr, const int* __restrict__ partials, int n) {
  int i = blockIdx.x * 1024 + threadIdx.x;
  if (i < n) row_ptr[i] += partials[blockIdx.x];
  if (i == 0) row_ptr[n] = partials[255];
}

__global__ __launch_bounds__(256) void fill_kernel(const int* __restrict__ ei,
    const float* __restrict__ ew, const float* __restrict__ dinv,
    const int* __restrict__ row_ptr, const int* __restrict__ rank,
    int2* __restrict__ epair, int E) {
  int e = blockIdx.x * 256 + threadIdx.x;
  if (e >= E) return;
  int s = ei[e], d = ei[E + e];
  float nw = dinv[s] * ew[e] * dinv[d];
  int p = row_ptr[d] + rank[e];
  epair[p] = make_int2(s, __float_as_int(nw));
}

// ---- aggregation: out[n] = sum_{e: dst=n} norm_e * xw[src_e] + dinv^2*xw[n] + b
// 16B uint4 gathers (8 halves/lane), F/8 lanes per node, x4 edge unroll.
template <int F, bool RELU, bool OUTF16>
__global__ __launch_bounds__(256) void agg_kernel(const unsigned short* __restrict__ xwh,
    const int* __restrict__ row_ptr, const int2* __restrict__ epair,
    const float* __restrict__ dinv, const float* __restrict__ bias,
    void* __restrict__ out, int Nn) {
  constexpr int LPN = F / 8;                  // lanes per node (8 dims each)
  int t = blockIdx.x * 256 + threadIdx.x;
  int node = t / LPN;
  int lane = t % LPN;
  if (node >= Nn) return;
  const uint4* xh = (const uint4*)xwh;        // 8 halves per uint4
  int start = row_ptr[node];
  int end = row_ptr[node + 1];
  float a0[8] = {}, a1[8] = {};               // two fma chains
  int p = start;
  for (; p + 4 <= end; p += 4) {
    int2 e0 = epair[p];
    int2 e1 = epair[p + 1];
    int2 e2 = epair[p + 2];
    int2 e3 = epair[p + 3];
    H8 u0, u1, u2, u3;
    u0.q = xh[(size_t)e0.x * LPN + lane];
    u1.q = xh[(size_t)e1.x * LPN + lane];
    u2.q = xh[(size_t)e2.x * LPN + lane];
    u3.q = xh[(size_t)e3.x * LPN + lane];
    float n0 = __int_as_float(e0.y), n1 = __int_as_float(e1.y);
    float n2 = __int_as_float(e2.y), n3 = __int_as_float(e3.y);
#pragma unroll
    for (int j = 0; j < 4; ++j) {
      float2 f0 = __half22float2(u0.h2[j]);
      float2 f1 = __half22float2(u1.h2[j]);
      float2 f2 = __half22float2(u2.h2[j]);
      float2 f3 = __half22float2(u3.h2[j]);
      a0[j * 2]     = fmaf(n0, f0.x, a0[j * 2]);
      a0[j * 2 + 1] = fmaf(n0, f0.y, a0[j * 2 + 1]);
      a1[j * 2]     = fmaf(n1, f1.x, a1[j * 2]);
      a1[j * 2 + 1] = fmaf(n1, f1.y, a1[j * 2 + 1]);
      a0[j * 2]     = fmaf(n2, f2.x, a0[j * 2]);
      a0[j * 2 + 1] = fmaf(n2, f2.y, a0[j * 2 + 1]);
      a1[j * 2]     = fmaf(n3, f3.x, a1[j * 2]);
      a1[j * 2 + 1] = fmaf(n3, f3.y, a1[j * 2 + 1]);
    }
  }
  for (; p < end; ++p) {
    int2 pr = epair[p];
    float nw = __int_as_float(pr.y);
    H8 u; u.q = xh[(size_t)pr.x * LPN + lane];
#pragma unroll
    for (int j = 0; j < 4; ++j) {
      float2 f = __half22float2(u.h2[j]);
      a0[j * 2]     = fmaf(nw, f.x, a0[j * 2]);
      a0[j * 2 + 1] = fmaf(nw, f.y, a0[j * 2 + 1]);
    }
  }
  float di = dinv[node];
  float sw = di * di;
  H8 su; su.q = xh[(size_t)node * LPN + lane];
#pragma unroll
  for (int j = 0; j < 4; ++j) {
    float2 f = __half22float2(su.h2[j]);
    a0[j * 2]     = fmaf(sw, f.x, a0[j * 2]);
    a0[j * 2 + 1] = fmaf(sw, f.y, a0[j * 2 + 1]);
  }
  float4 b0 = ((const float4*)bias)[lane * 2];
  float4 b1 = ((const float4*)bias)[lane * 2 + 1];
  float o[8];
  o[0] = a0[0] + a1[0] + b0.x; o[1] = a0[1] + a1[1] + b0.y;
  o[2] = a0[2] + a1[2] + b0.z; o[3] = a0[3] + a1[3] + b0.w;
  o[4] = a0[4] + a1[4] + b1.x; o[5] = a0[5] + a1[5] + b1.y;
  o[6] = a0[6] + a1[6] + b1.z; o[7] = a0[7] + a1[7] + b1.w;
  if (RELU) {
#pragma unroll
    for (int j = 0; j < 8; ++j) o[j] = fmaxf(o[j], 0.f);
  }
  if constexpr (OUTF16) {
    H8 w;
#pragma unroll
    for (int j = 0; j < 4; ++j)
      w.h2[j] = __float22half2_rn(make_float2(o[j * 2], o[j * 2 + 1]));
    ((uint4*)out)[(size_t)node * LPN + lane] = w.q;
  } else {
    float4* of = (float4*)out + (size_t)node * LPN * 2 + lane * 2;
    of[0] = make_float4(o[0], o[1], o[2], o[3]);
    of[1] = make_float4(o[4], o[5], o[6], o[7]);
  }
}

// ---------------------------------------------------------------------------
extern "C" void kernel_launch(void* const* d_in, const int* in_sizes, int n_in,
                              void* d_out, int out_size, void* d_ws, size_t ws_size,
                              hipStream_t stream) {
  const float* x  = (const float*)d_in[0];
  const int*   ei = (const int*)d_in[1];     // int32, [2,E] flat
  const float* ew = (const float*)d_in[2];
  const float* W1 = (const float*)d_in[3];
  const float* b1 = (const float*)d_in[4];
  const float* W2 = (const float*)d_in[5];
  const float* b2 = (const float*)d_in[6];
  const float* W3 = (const float*)d_in[7];
  const float* b3 = (const float*)d_in[8];

  const int N = in_sizes[0] / 128;           // 100000
  const int E = in_sizes[2];                 // 1600000

  // workspace carve (256B aligned)
  char* ws = (char*)d_ws;
  size_t off = 0;
  auto carve = [&](size_t bytes) -> void* {
    void* p = ws + off;
    off += (bytes + 255) & ~(size_t)255;
    return p;
  };
  unsigned long long* packed = (unsigned long long*)carve((size_t)N * 8);
  int*   rank    = (int*)carve((size_t)E * 4);
  float* dinv    = (float*)carve((size_t)N * 4);
  int*   row_ptr = (int*)carve((size_t)(N + 1) * 4);
  int*   parts   = (int*)carve(256 * 4);
  int2*  epair   = (int2*)carve((size_t)E * 8);
  unsigned short* bufH = (unsigned short*)carve((size_t)N * 128 * 2);  // fp16 xw
  unsigned short* bufI = (unsigned short*)carve((size_t)N * 128 * 2);  // fp16 h
  (void)ws_size; (void)n_in; (void)out_size;

  const int nThreads = 256;
  int gE  = (E + nThreads - 1) / nThreads;
  int nb  = (N + 1023) / 1024;               // scan blocks (98)
  const int gMM = (N + 63) / 64;             // 1563 MFMA row-blocks
  int gAgg128 = (N * 16 + nThreads - 1) / nThreads;
  int gAgg64  = (N * 8 + nThreads - 1) / nThreads;

  // --- D1: edge_pass (first) co-dispatched with 32KB-LDS layer-1 GEMM ---
  hipMemsetAsync(packed, 0, (size_t)N * 8, stream);
  pre_gemm_fused_kernel<<<gE + 2 * gMM, nThreads, 0, stream>>>(
      x, W1, bufH, N, ei, ew, packed, rank, E, gE);

  // --- graph preprocessing tail (dinv fused into scanA) ---
  scanA<<<nb, 1024, 0, stream>>>(packed, row_ptr, parts, dinv, N);
  scanB<<<1, 128, 0, stream>>>(parts, nb);
  scanC<<<nb, 1024, 0, stream>>>(row_ptr, parts, N);
  fill_kernel<<<gE, nThreads, 0, stream>>>(ei, ew, dinv, row_ptr, rank, epair, E);

  // --- layer 1 aggregate -> fp16 h1 ---
  agg_kernel<128, true, true><<<gAgg128, nThreads, 0, stream>>>(bufH, row_ptr, epair, dinv, b1, bufI, N);

  // --- layer 2: gemm (fp16 A) -> bufH; agg -> fp16 h2 ---
  gemm_mfma_kernel<128><<<gMM, nThreads, 0, stream>>>(bufI, W2, bufH, N);
  agg_kernel<128, true, true><<<gAgg128, nThreads, 0, stream>>>(bufH, row_ptr, epair, dinv, b2, bufI, N);

  // --- layer 3: gemm 64-wide (fp16 A) -> bufH; agg -> fp32 d_out ---
  gemm_mfma_kernel<64><<<gMM, nThreads, 0, stream>>>(bufI, W3, bufH, N);
  agg_kernel<64, false, false><<<gAgg64, nThreads, 0, stream>>>(bufH, row_ptr, epair, dinv, b3, d_out, N);
}

// Round 14
// 333.842 us; speedup vs baseline: 1.0966x; 1.0227x over previous
//
#include <hip/hip_runtime.h>
#include <hip/hip_fp16.h>
#include <math.h>

// ---------------------------------------------------------------------------
// GCN 3-layer forward on MI355X.
// Round 14 change: gemm2/3 (23us each vs 8us traffic floor) were dominated by
// per-block 64KB W staging (100MB LDS-write traffic) + 4x-redundant B-frag
// reads at 2 blocks/CU. Each wave now computes TWO 16-row A-fragments per
// B-fragment read -> block covers 128 rows, grid halves, staging traffic and
// per-MFMA LDS reads halve. Same for the fused 64-col-slice gemm.
// ---------------------------------------------------------------------------

typedef __bf16 bf16x8 __attribute__((ext_vector_type(8)));
typedef float f32x4 __attribute__((ext_vector_type(4)));

union BF8 {
  unsigned short u[8];
  uint4 q;
  bf16x8 v;
};

union H8 {
  uint4 q;
  __half2 h2[4];
};

__device__ __forceinline__ unsigned short rne_bf16(float f) {
  unsigned u = __float_as_uint(f);
  u += 0x7fff + ((u >> 16) & 1);
  return (unsigned short)(u >> 16);
}
__device__ __forceinline__ float bf16_to_f(unsigned short h) {
  return __uint_as_float((unsigned)h << 16);
}

__device__ __forceinline__ void split_f32_to_bf(const float* av, BF8& ah, BF8& al) {
#pragma unroll
  for (int j = 0; j < 8; ++j) {
    unsigned short hb = rne_bf16(av[j]);
    ah.u[j] = hb;
    al.u[j] = rne_bf16(av[j] - bf16_to_f(hb));
  }
}

// ---- 64-col-slice MFMA gemm body (32KB LDS), 128 rows/block ---------------
// fp32 A; two 16-row fragments per wave share each B-fragment read.
__device__ __forceinline__ void gemm_body_slice(const float* __restrict__ A,
    const float* __restrict__ W, int ldw, int col0,
    unsigned short* __restrict__ Ch, int ldc, int M, int bid) {
  constexpr int NF = 4;
  __shared__ __align__(16) unsigned short WT[2][64][128];
  const int t = threadIdx.x;
#pragma unroll
  for (int it = 0; it < 4; ++it) {
    int n = t & 63;
    int kc = it * 4 + (t >> 6);
    int k0 = kc * 8;
    BF8 hh, ll;
#pragma unroll
    for (int j = 0; j < 8; ++j) {
      float w = W[(size_t)(k0 + j) * ldw + col0 + n];
      unsigned short hb = rne_bf16(w);
      hh.u[j] = hb;
      ll.u[j] = rne_bf16(w - bf16_to_f(hb));
    }
    int kk = k0 ^ ((n & 7) << 3);
    *(uint4*)&WT[0][n][kk] = hh.q;
    *(uint4*)&WT[1][n][kk] = ll.q;
  }
  __syncthreads();

  const int wv = t >> 6;
  const int l = t & 63;
  const int lr = l & 15;
  const int lg = l >> 4;
  const int r0 = bid * 128 + wv * 32 + lr;
  const int r1 = r0 + 16;
  const bool v0 = r0 < M, v1 = r1 < M;
  const float* a0p = A + (size_t)r0 * 128;
  const float* a1p = A + (size_t)r1 * 128;

  f32x4 acc0[NF] = {}, acc1[NF] = {};
  float4 p00 = make_float4(0.f, 0.f, 0.f, 0.f), p01 = p00, p10 = p00, p11 = p00;
  if (v0) { p00 = *(const float4*)&a0p[lg * 8]; p01 = *(const float4*)&a0p[lg * 8 + 4]; }
  if (v1) { p10 = *(const float4*)&a1p[lg * 8]; p11 = *(const float4*)&a1p[lg * 8 + 4]; }
#pragma unroll 1
  for (int ks = 0; ks < 4; ++ks) {
    int nkb = ((ks < 3) ? (ks + 1) * 32 : ks * 32) + lg * 8;
    float4 q00 = make_float4(0.f, 0.f, 0.f, 0.f), q01 = q00, q10 = q00, q11 = q00;
    if (v0) { q00 = *(const float4*)&a0p[nkb]; q01 = *(const float4*)&a0p[nkb + 4]; }
    if (v1) { q10 = *(const float4*)&a1p[nkb]; q11 = *(const float4*)&a1p[nkb + 4]; }
    float av0[8] = {p00.x, p00.y, p00.z, p00.w, p01.x, p01.y, p01.z, p01.w};
    float av1[8] = {p10.x, p10.y, p10.z, p10.w, p11.x, p11.y, p11.z, p11.w};
    BF8 ah0, al0, ah1, al1;
    split_f32_to_bf(av0, ah0, al0);
    split_f32_to_bf(av1, ah1, al1);
    int kidx = ks * 32 + lg * 8;
#pragma unroll
    for (int nf = 0; nf < NF; ++nf) {
      int n = nf * 16 + lr;
      int kk = kidx ^ ((n & 7) << 3);
      BF8 bh, bl;
      bh.q = *(const uint4*)&WT[0][n][kk];
      bl.q = *(const uint4*)&WT[1][n][kk];
      acc0[nf] = __builtin_amdgcn_mfma_f32_16x16x32_bf16(ah0.v, bh.v, acc0[nf], 0, 0, 0);
      acc0[nf] = __builtin_amdgcn_mfma_f32_16x16x32_bf16(al0.v, bh.v, acc0[nf], 0, 0, 0);
      acc0[nf] = __builtin_amdgcn_mfma_f32_16x16x32_bf16(ah0.v, bl.v, acc0[nf], 0, 0, 0);
      acc1[nf] = __builtin_amdgcn_mfma_f32_16x16x32_bf16(ah1.v, bh.v, acc1[nf], 0, 0, 0);
      acc1[nf] = __builtin_amdgcn_mfma_f32_16x16x32_bf16(al1.v, bh.v, acc1[nf], 0, 0, 0);
      acc1[nf] = __builtin_amdgcn_mfma_f32_16x16x32_bf16(ah1.v, bl.v, acc1[nf], 0, 0, 0);
    }
    p00 = q00; p01 = q01; p10 = q10; p11 = q11;
  }
  const int ob = bid * 128 + wv * 32 + lg * 4;
#pragma unroll
  for (int j = 0; j < 4; ++j) {
    int orow = ob + j;
    if (orow < M) {
      unsigned short* hr = Ch + (size_t)orow * ldc + col0;
#pragma unroll
      for (int nf = 0; nf < NF; ++nf)
        hr[nf * 16 + lr] = __half_as_ushort(__float2half(acc0[nf][j]));
    }
    int orow1 = ob + 16 + j;
    if (orow1 < M) {
      unsigned short* hr = Ch + (size_t)orow1 * ldc + col0;
#pragma unroll
      for (int nf = 0; nf < NF; ++nf)
        hr[nf * 16 + lr] = __half_as_ushort(__float2half(acc1[nf][j]));
    }
  }
}

// fused dispatch: blocks [0,edgeBlocks) = edge_pass; rest = layer-1 GEMM.
__global__ __launch_bounds__(256) void pre_gemm_fused_kernel(
    const float* __restrict__ x, const float* __restrict__ W1,
    unsigned short* __restrict__ Ch, int M,
    const int* __restrict__ ei, const float* __restrict__ ew,
    unsigned long long* __restrict__ packed, int* __restrict__ rank,
    int E, int edgeBlocks) {
  if ((int)blockIdx.x < edgeBlocks) {
    int e = blockIdx.x * 256 + threadIdx.x;
    if (e >= E) return;
    int d = ei[E + e];
    unsigned wfix = (unsigned)__float2uint_rn(ew[e] * 16777216.0f);  // Q24
    unsigned long long inc = (1ULL << 32) | (unsigned long long)wfix;
    unsigned long long old = atomicAdd(&packed[d], inc);
    rank[e] = (int)(old >> 32);
  } else {
    int g = blockIdx.x - edgeBlocks;
    gemm_body_slice(x, W1, 128, (g & 1) * 64, Ch, 128, M, g >> 1);
  }
}

// ---- LDS-staged full-width MFMA gemm (layers 2,3; fp16 A), 128 rows/block --
template <int NCOL>
__global__ __launch_bounds__(256) void gemm_mfma_kernel(
    const unsigned short* __restrict__ Ah, const float* __restrict__ W,
    unsigned short* __restrict__ Ch, int M) {
  constexpr int NF = NCOL / 16;
  __shared__ __align__(16) unsigned short WT[2][NCOL][128];
  const int t = threadIdx.x;
  constexpr int KC_PER_IT = 256 / NCOL;
#pragma unroll
  for (int it = 0; it < 16 / KC_PER_IT; ++it) {
    int n = t % NCOL;
    int kc = it * KC_PER_IT + t / NCOL;
    int k0 = kc * 8;
    BF8 hh, ll;
#pragma unroll
    for (int j = 0; j < 8; ++j) {
      float w = W[(size_t)(k0 + j) * NCOL + n];
      unsigned short hb = rne_bf16(w);
      hh.u[j] = hb;
      ll.u[j] = rne_bf16(w - bf16_to_f(hb));
    }
    int kk = k0 ^ ((n & 7) << 3);
    *(uint4*)&WT[0][n][kk] = hh.q;
    *(uint4*)&WT[1][n][kk] = ll.q;
  }
  __syncthreads();

  const int wv = t >> 6;
  const int l = t & 63;
  const int lr = l & 15;
  const int lg = l >> 4;
  const int r0 = blockIdx.x * 128 + wv * 32 + lr;
  const int r1 = r0 + 16;
  const bool v0 = r0 < M, v1 = r1 < M;
  const unsigned short* a0p = Ah + (size_t)r0 * 128;
  const unsigned short* a1p = Ah + (size_t)r1 * 128;

  f32x4 acc0[NF] = {}, acc1[NF] = {};
  uint4 ph0 = make_uint4(0, 0, 0, 0), ph1 = ph0;
  if (v0) ph0 = *(const uint4*)&a0p[lg * 8];
  if (v1) ph1 = *(const uint4*)&a1p[lg * 8];
#pragma unroll 1
  for (int ks = 0; ks < 4; ++ks) {
    int nkb = ((ks < 3) ? (ks + 1) * 32 : ks * 32) + lg * 8;
    uint4 qh0 = make_uint4(0, 0, 0, 0), qh1 = qh0;
    if (v0) qh0 = *(const uint4*)&a0p[nkb];
    if (v1) qh1 = *(const uint4*)&a1p[nkb];
    float av0[8], av1[8];
    {
      H8 uu; uu.q = ph0;
#pragma unroll
      for (int j = 0; j < 4; ++j) {
        float2 f = __half22float2(uu.h2[j]);
        av0[j * 2] = f.x; av0[j * 2 + 1] = f.y;
      }
      uu.q = ph1;
#pragma unroll
      for (int j = 0; j < 4; ++j) {
        float2 f = __half22float2(uu.h2[j]);
        av1[j * 2] = f.x; av1[j * 2 + 1] = f.y;
      }
    }
    BF8 ah0, al0, ah1, al1;
    split_f32_to_bf(av0, ah0, al0);
    split_f32_to_bf(av1, ah1, al1);
    int kidx = ks * 32 + lg * 8;
#pragma unroll
    for (int nf = 0; nf < NF; ++nf) {
      int n = nf * 16 + lr;
      int kk = kidx ^ ((n & 7) << 3);
      BF8 bh, bl;
      bh.q = *(const uint4*)&WT[0][n][kk];
      bl.q = *(const uint4*)&WT[1][n][kk];
      acc0[nf] = __builtin_amdgcn_mfma_f32_16x16x32_bf16(ah0.v, bh.v, acc0[nf], 0, 0, 0);
      acc0[nf] = __builtin_amdgcn_mfma_f32_16x16x32_bf16(al0.v, bh.v, acc0[nf], 0, 0, 0);
      acc0[nf] = __builtin_amdgcn_mfma_f32_16x16x32_bf16(ah0.v, bl.v, acc0[nf], 0, 0, 0);
      acc1[nf] = __builtin_amdgcn_mfma_f32_16x16x32_bf16(ah1.v, bh.v, acc1[nf], 0, 0, 0);
      acc1[nf] = __builtin_amdgcn_mfma_f32_16x16x32_bf16(al1.v, bh.v, acc1[nf], 0, 0, 0);
      acc1[nf] = __builtin_amdgcn_mfma_f32_16x16x32_bf16(ah1.v, bl.v, acc1[nf], 0, 0, 0);
    }
    ph0 = qh0; ph1 = qh1;
  }
  const int ob = blockIdx.x * 128 + wv * 32 + lg * 4;
#pragma unroll
  for (int j = 0; j < 4; ++j) {
    int orow = ob + j;
    if (orow < M) {
      unsigned short* hr = Ch + (size_t)orow * NCOL;
#pragma unroll
      for (int nf = 0; nf < NF; ++nf)
        hr[nf * 16 + lr] = __half_as_ushort(__float2half(acc0[nf][j]));
    }
    int orow1 = ob + 16 + j;
    if (orow1 < M) {
      unsigned short* hr = Ch + (size_t)orow1 * NCOL;
#pragma unroll
      for (int nf = 0; nf < NF; ++nf)
        hr[nf * 16 + lr] = __half_as_ushort(__float2half(acc1[nf][j]));
    }
  }
}

// ---- scanA with fused dinv: exclusive scan of counts + dinv[i] -------------
__global__ __launch_bounds__(1024) void scanA(const unsigned long long* __restrict__ packed,
    int* __restrict__ row_ptr, int* __restrict__ partials,
    float* __restrict__ dinv, int n) {
  __shared__ int sd[1024];
  int t = threadIdx.x;
  int i = blockIdx.x * 1024 + t;
  unsigned long long pv = (i < n) ? packed[i] : 0ULL;
  int v = (int)(pv >> 32);
  if (i < n) {
    float deg = 1.0f + (float)(unsigned)(pv & 0xffffffffULL) * (1.0f / 16777216.0f);
    dinv[i] = 1.0f / sqrtf(deg);
  }
  sd[t] = v;
  __syncthreads();
  for (int off = 1; off < 1024; off <<= 1) {
    int u = (t >= off) ? sd[t - off] : 0;
    __syncthreads();
    sd[t] += u;
    __syncthreads();
  }
  int incl = sd[t];
  if (i < n) row_ptr[i] = incl - v;
  if (t == 1023) partials[blockIdx.x] = incl;
}

__global__ __launch_bounds__(128) void scanB(int* partials, int nb) {
  __shared__ int sd[128];
  int t = threadIdx.x;
  int v = (t < nb) ? partials[t] : 0;
  sd[t] = v;
  __syncthreads();
  for (int off = 1; off < 128; off <<= 1) {
    int u = (t >= off) ? sd[t - off] : 0;
    __syncthreads();
    sd[t] += u;
    __syncthreads();
  }
  int incl = sd[t];
  partials[t] = incl - v;
  if (t == nb - 1) partials[255] = incl;
}

__global__ __launch_bounds__(1024) void scanC(int* row_ptr, const int* __restrict__ partials, int n) {
  int i = blockIdx.x * 1024 + threadIdx.x;
  if (i < n) row_ptr[i] += partials[blockIdx.x];
  if (i == 0) row_ptr[n] = partials[255];
}

__global__ __launch_bounds__(256) void fill_kernel(const int* __restrict__ ei,
    const float* __restrict__ ew, const float* __restrict__ dinv,
    const int* __restrict__ row_ptr, const int* __restrict__ rank,
    int2* __restrict__ epair, int E) {
  int e = blockIdx.x * 256 + threadIdx.x;
  if (e >= E) return;
  int s = ei[e], d = ei[E + e];
  float nw = dinv[s] * ew[e] * dinv[d];
  int p = row_ptr[d] + rank[e];
  epair[p] = make_int2(s, __float_as_int(nw));
}

// ---- aggregation: out[n] = sum_{e: dst=n} norm_e * xw[src_e] + dinv^2*xw[n] + b
// 16B uint4 gathers (8 halves/lane), F/8 lanes per node, x4 edge unroll.
template <int F, bool RELU, bool OUTF16>
__global__ __launch_bounds__(256) void agg_kernel(const unsigned short* __restrict__ xwh,
    const int* __restrict__ row_ptr, const int2* __restrict__ epair,
    const float* __restrict__ dinv, const float* __restrict__ bias,
    void* __restrict__ out, int Nn) {
  constexpr int LPN = F / 8;                  // lanes per node (8 dims each)
  int t = blockIdx.x * 256 + threadIdx.x;
  int node = t / LPN;
  int lane = t % LPN;
  if (node >= Nn) return;
  const uint4* xh = (const uint4*)xwh;        // 8 halves per uint4
  int start = row_ptr[node];
  int end = row_ptr[node + 1];
  float a0[8] = {}, a1[8] = {};               // two fma chains
  int p = start;
  for (; p + 4 <= end; p += 4) {
    int2 e0 = epair[p];
    int2 e1 = epair[p + 1];
    int2 e2 = epair[p + 2];
    int2 e3 = epair[p + 3];
    H8 u0, u1, u2, u3;
    u0.q = xh[(size_t)e0.x * LPN + lane];
    u1.q = xh[(size_t)e1.x * LPN + lane];
    u2.q = xh[(size_t)e2.x * LPN + lane];
    u3.q = xh[(size_t)e3.x * LPN + lane];
    float n0 = __int_as_float(e0.y), n1 = __int_as_float(e1.y);
    float n2 = __int_as_float(e2.y), n3 = __int_as_float(e3.y);
#pragma unroll
    for (int j = 0; j < 4; ++j) {
      float2 f0 = __half22float2(u0.h2[j]);
      float2 f1 = __half22float2(u1.h2[j]);
      float2 f2 = __half22float2(u2.h2[j]);
      float2 f3 = __half22float2(u3.h2[j]);
      a0[j * 2]     = fmaf(n0, f0.x, a0[j * 2]);
      a0[j * 2 + 1] = fmaf(n0, f0.y, a0[j * 2 + 1]);
      a1[j * 2]     = fmaf(n1, f1.x, a1[j * 2]);
      a1[j * 2 + 1] = fmaf(n1, f1.y, a1[j * 2 + 1]);
      a0[j * 2]     = fmaf(n2, f2.x, a0[j * 2]);
      a0[j * 2 + 1] = fmaf(n2, f2.y, a0[j * 2 + 1]);
      a1[j * 2]     = fmaf(n3, f3.x, a1[j * 2]);
      a1[j * 2 + 1] = fmaf(n3, f3.y, a1[j * 2 + 1]);
    }
  }
  for (; p < end; ++p) {
    int2 pr = epair[p];
    float nw = __int_as_float(pr.y);
    H8 u; u.q = xh[(size_t)pr.x * LPN + lane];
#pragma unroll
    for (int j = 0; j < 4; ++j) {
      float2 f = __half22float2(u.h2[j]);
      a0[j * 2]     = fmaf(nw, f.x, a0[j * 2]);
      a0[j * 2 + 1] = fmaf(nw, f.y, a0[j * 2 + 1]);
    }
  }
  float di = dinv[node];
  float sw = di * di;
  H8 su; su.q = xh[(size_t)node * LPN + lane];
#pragma unroll
  for (int j = 0; j < 4; ++j) {
    float2 f = __half22float2(su.h2[j]);
    a0[j * 2]     = fmaf(sw, f.x, a0[j * 2]);
    a0[j * 2 + 1] = fmaf(sw, f.y, a0[j * 2 + 1]);
  }
  float4 b0 = ((const float4*)bias)[lane * 2];
  float4 b1 = ((const float4*)bias)[lane * 2 + 1];
  float o[8];
  o[0] = a0[0] + a1[0] + b0.x; o[1] = a0[1] + a1[1] + b0.y;
  o[2] = a0[2] + a1[2] + b0.z; o[3] = a0[3] + a1[3] + b0.w;
  o[4] = a0[4] + a1[4] + b1.x; o[5] = a0[5] + a1[5] + b1.y;
  o[6] = a0[6] + a1[6] + b1.z; o[7] = a0[7] + a1[7] + b1.w;
  if (RELU) {
#pragma unroll
    for (int j = 0; j < 8; ++j) o[j] = fmaxf(o[j], 0.f);
  }
  if constexpr (OUTF16) {
    H8 w;
#pragma unroll
    for (int j = 0; j < 4; ++j)
      w.h2[j] = __float22half2_rn(make_float2(o[j * 2], o[j * 2 + 1]));
    ((uint4*)out)[(size_t)node * LPN + lane] = w.q;
  } else {
    float4* of = (float4*)out + (size_t)node * LPN * 2 + lane * 2;
    of[0] = make_float4(o[0], o[1], o[2], o[3]);
    of[1] = make_float4(o[4], o[5], o[6], o[7]);
  }
}

// ---------------------------------------------------------------------------
extern "C" void kernel_launch(void* const* d_in, const int* in_sizes, int n_in,
                              void* d_out, int out_size, void* d_ws, size_t ws_size,
                              hipStream_t stream) {
  const float* x  = (const float*)d_in[0];
  const int*   ei = (const int*)d_in[1];     // int32, [2,E] flat
  const float* ew = (const float*)d_in[2];
  const float* W1 = (const float*)d_in[3];
  const float* b1 = (const float*)d_in[4];
  const float* W2 = (const float*)d_in[5];
  const float* b2 = (const float*)d_in[6];
  const float* W3 = (const float*)d_in[7];
  const float* b3 = (const float*)d_in[8];

  const int N = in_sizes[0] / 128;           // 100000
  const int E = in_sizes[2];                 // 1600000

  // workspace carve (256B aligned)
  char* ws = (char*)d_ws;
  size_t off = 0;
  auto carve = [&](size_t bytes) -> void* {
    void* p = ws + off;
    off += (bytes + 255) & ~(size_t)255;
    return p;
  };
  unsigned long long* packed = (unsigned long long*)carve((size_t)N * 8);
  int*   rank    = (int*)carve((size_t)E * 4);
  float* dinv    = (float*)carve((size_t)N * 4);
  int*   row_ptr = (int*)carve((size_t)(N + 1) * 4);
  int*   parts   = (int*)carve(256 * 4);
  int2*  epair   = (int2*)carve((size_t)E * 8);
  unsigned short* bufH = (unsigned short*)carve((size_t)N * 128 * 2);  // fp16 xw
  unsigned short* bufI = (unsigned short*)carve((size_t)N * 128 * 2);  // fp16 h
  (void)ws_size; (void)n_in; (void)out_size;

  const int nThreads = 256;
  int gE  = (E + nThreads - 1) / nThreads;
  int nb  = (N + 1023) / 1024;               // scan blocks (98)
  const int gMM = (N + 127) / 128;           // 782 MFMA row-blocks (128 rows)
  int gAgg128 = (N * 16 + nThreads - 1) / nThreads;
  int gAgg64  = (N * 8 + nThreads - 1) / nThreads;

  // --- D1: edge_pass (first) co-dispatched with 32KB-LDS layer-1 GEMM ---
  hipMemsetAsync(packed, 0, (size_t)N * 8, stream);
  pre_gemm_fused_kernel<<<gE + 2 * gMM, nThreads, 0, stream>>>(
      x, W1, bufH, N, ei, ew, packed, rank, E, gE);

  // --- graph preprocessing tail (dinv fused into scanA) ---
  scanA<<<nb, 1024, 0, stream>>>(packed, row_ptr, parts, dinv, N);
  scanB<<<1, 128, 0, stream>>>(parts, nb);
  scanC<<<nb, 1024, 0, stream>>>(row_ptr, parts, N);
  fill_kernel<<<gE, nThreads, 0, stream>>>(ei, ew, dinv, row_ptr, rank, epair, E);

  // --- layer 1 aggregate -> fp16 h1 ---
  agg_kernel<128, true, true><<<gAgg128, nThreads, 0, stream>>>(bufH, row_ptr, epair, dinv, b1, bufI, N);

  // --- layer 2: gemm (fp16 A) -> bufH; agg -> fp16 h2 ---
  gemm_mfma_kernel<128><<<gMM, nThreads, 0, stream>>>(bufI, W2, bufH, N);
  agg_kernel<128, true, true><<<gAgg128, nThreads, 0, stream>>>(bufH, row_ptr, epair, dinv, b2, bufI, N);

  // --- layer 3: gemm 64-wide (fp16 A) -> bufH; agg -> fp32 d_out ---
  gemm_mfma_kernel<64><<<gMM, nThreads, 0, stream>>>(bufI, W3, bufH, N);
  agg_kernel<64, false, false><<<gAgg64, nThreads, 0, stream>>>(bufH, row_ptr, epair, dinv, b3, d_out, N);
}